// Round 1
// baseline (196.729 us; speedup 1.0000x reference)
//
#include <hip/hip_runtime.h>
#include <hip/hip_bf16.h>
#include <cstdint>

#define NH 8
#define DM 512
#define DH 64
#define NB 4
#define SL 1024

typedef __attribute__((ext_vector_type(8))) short bf16x8;
typedef __attribute__((ext_vector_type(4))) float f32x4;

static __device__ __forceinline__ float bf2f(short s) {
  union { unsigned int u; float f; } c;
  c.u = ((unsigned int)(unsigned short)s) << 16;
  return c.f;
}
static __device__ __forceinline__ unsigned short f2bfbits(float f) {
  union { float f; unsigned int u; } c; c.f = f;
  unsigned int lsb = (c.u >> 16) & 1u;
  unsigned int r = c.u + 0x7fffu + lsb;   // RNE (inputs are finite/normal)
  return (unsigned short)(r >> 16);
}

// ---------- 1) fp32 -> bf16 for q,k,v (each [4096,512]) ----------
__global__ __launch_bounds__(256) void k_cvt_act(
    const float* __restrict__ q, const float* __restrict__ k, const float* __restrict__ v,
    ushort* __restrict__ qb, ushort* __restrict__ kb, ushort* __restrict__ vb) {
  int i = blockIdx.x * 256 + threadIdx.x;   // float4 group, 524288 total
  {
    float4 f = ((const float4*)q)[i];
    ushort4 r = { f2bfbits(f.x), f2bfbits(f.y), f2bfbits(f.z), f2bfbits(f.w) };
    *(ushort4*)(qb + 4 * i) = r;
  }
  {
    float4 f = ((const float4*)k)[i];
    ushort4 r = { f2bfbits(f.x), f2bfbits(f.y), f2bfbits(f.z), f2bfbits(f.w) };
    *(ushort4*)(kb + 4 * i) = r;
  }
  {
    float4 f = ((const float4*)v)[i];
    ushort4 r = { f2bfbits(f.x), f2bfbits(f.y), f2bfbits(f.z), f2bfbits(f.w) };
    *(ushort4*)(vb + 4 * i) = r;
  }
}

// ---------- 2) transpose-convert W [512,512] -> W^T bf16 ----------
__global__ __launch_bounds__(256) void k_cvt_wT(
    const float* __restrict__ w0, const float* __restrict__ w1, const float* __restrict__ w2,
    ushort* __restrict__ o0, ushort* __restrict__ o1, ushort* __restrict__ o2) {
  __shared__ ushort tile[64][65];
  const float* src = blockIdx.z == 0 ? w0 : (blockIdx.z == 1 ? w1 : w2);
  ushort* dst = blockIdx.z == 0 ? o0 : (blockIdx.z == 1 ? o1 : o2);
  int k0 = blockIdx.x * 64, n0 = blockIdx.y * 64;
  int t = threadIdx.x;
  #pragma unroll
  for (int i = 0; i < 16; ++i) {
    int lin = t + i * 256, r = lin >> 6, c = lin & 63;
    tile[r][c] = f2bfbits(src[(size_t)(k0 + r) * DM + n0 + c]);
  }
  __syncthreads();
  #pragma unroll
  for (int i = 0; i < 16; ++i) {
    int lin = t + i * 256, r = lin >> 6, c = lin & 63;
    dst[(size_t)(n0 + r) * DM + k0 + c] = tile[c][r];
  }
}

// ---------- 3) w_fc [64,512] -> bf16 ----------
__global__ __launch_bounds__(256) void k_cvt_wfc(const float* __restrict__ w, ushort* __restrict__ o) {
  int i = blockIdx.x * 256 + threadIdx.x;   // 8192 float4 groups
  float4 f = ((const float4*)w)[i];
  ushort4 r = { f2bfbits(f.x), f2bfbits(f.y), f2bfbits(f.z), f2bfbits(f.w) };
  *(ushort4*)(o + 4 * i) = r;
}

// ---------- 4) projection GEMM: [4096,512]bf16 @ W^T -> heads ----------
// z=0: Q (scale 1/8, out [B,H,L,64]); z=1: K (out [B,H,L,64]); z=2: V (out [B,H,64,L] transposed)
__global__ __launch_bounds__(256) void k_proj(
    const ushort* __restrict__ qb, const ushort* __restrict__ kb, const ushort* __restrict__ vb,
    const ushort* __restrict__ wqT, const ushort* __restrict__ wkT, const ushort* __restrict__ wvT,
    ushort* __restrict__ Qh, ushort* __restrict__ Kh, ushort* __restrict__ VhT) {
  int z = blockIdx.z;
  const ushort* A = z == 0 ? qb : (z == 1 ? kb : vb);
  const ushort* W = z == 0 ? wqT : (z == 1 ? wkT : wvT);
  ushort* Out = z == 0 ? Qh : (z == 1 ? Kh : VhT);
  float scale = z == 0 ? 0.125f : 1.0f;

  int wid = threadIdx.x >> 6, l = threadIdx.x & 63;
  int lr = l & 15, lg = l >> 4;
  int row0 = blockIdx.x * 64 + wid * 16;
  int col0 = blockIdx.y * 64;
  const ushort* Arow = A + (size_t)(row0 + lr) * DM + lg * 8;

  f32x4 acc0 = {0.f, 0.f, 0.f, 0.f}, acc1 = acc0, acc2 = acc0, acc3 = acc0;
  #pragma unroll 4
  for (int kt = 0; kt < 16; ++kt) {
    bf16x8 a = *(const bf16x8*)(Arow + kt * 32);
    bf16x8 b0 = *(const bf16x8*)(W + (size_t)(col0 + 0 * 16 + lr) * DM + kt * 32 + lg * 8);
    bf16x8 b1 = *(const bf16x8*)(W + (size_t)(col0 + 1 * 16 + lr) * DM + kt * 32 + lg * 8);
    bf16x8 b2 = *(const bf16x8*)(W + (size_t)(col0 + 2 * 16 + lr) * DM + kt * 32 + lg * 8);
    bf16x8 b3 = *(const bf16x8*)(W + (size_t)(col0 + 3 * 16 + lr) * DM + kt * 32 + lg * 8);
    acc0 = __builtin_amdgcn_mfma_f32_16x16x32_bf16(a, b0, acc0, 0, 0, 0);
    acc1 = __builtin_amdgcn_mfma_f32_16x16x32_bf16(a, b1, acc1, 0, 0, 0);
    acc2 = __builtin_amdgcn_mfma_f32_16x16x32_bf16(a, b2, acc2, 0, 0, 0);
    acc3 = __builtin_amdgcn_mfma_f32_16x16x32_bf16(a, b3, acc3, 0, 0, 0);
  }
  f32x4 accs[4] = {acc0, acc1, acc2, acc3};
  #pragma unroll
  for (int ct = 0; ct < 4; ++ct) {
    int gcol = col0 + ct * 16 + lr;
    int h = gcol >> 6, d = gcol & 63;
    #pragma unroll
    for (int r = 0; r < 4; ++r) {
      int grow = row0 + lg * 4 + r;
      int bb = grow >> 10, li = grow & 1023;
      float val = accs[ct][r] * scale;
      size_t addr;
      if (z == 2) addr = ((size_t)((bb * NH + h) * DH + d)) * SL + li;
      else        addr = ((size_t)((bb * NH + h) * SL + li)) * DH + d;
      Out[addr] = f2bfbits(val);
    }
  }
}

// ---------- 5) fused attention: QK^T -> softmax -> attn out + PV ----------
__global__ __launch_bounds__(256) void k_attn(
    const ushort* __restrict__ Qh, const ushort* __restrict__ Kh, const ushort* __restrict__ VhT,
    float* __restrict__ attn_out, float* __restrict__ O) {
  __shared__ __align__(16) float S[16][1028];     // padded: stride%32==4 banks
  __shared__ __align__(16) ushort P[16][1032];    // padded: b128 reads conflict-free

  int rt = blockIdx.x, h = blockIdx.y, bb = blockIdx.z;
  int bh = bb * NH + h;
  int wid = threadIdx.x >> 6, l = threadIdx.x & 63;
  int lr = l & 15, lg = l >> 4;

  const ushort* Qbase = Qh + ((size_t)(bh * SL + rt * 16 + lr)) * DH + lg * 8;
  bf16x8 aQ0 = *(const bf16x8*)(Qbase);
  bf16x8 aQ1 = *(const bf16x8*)(Qbase + 32);
  const ushort* Kbase = Kh + (size_t)bh * SL * DH;

  // QK^T: wave wid covers cols [wid*256, wid*256+256)
  #pragma unroll 4
  for (int ct = 0; ct < 16; ++ct) {
    int col0 = wid * 256 + ct * 16;
    const ushort* kp = Kbase + (size_t)(col0 + lr) * DH + lg * 8;
    bf16x8 b0 = *(const bf16x8*)(kp);
    bf16x8 b1 = *(const bf16x8*)(kp + 32);
    f32x4 acc = {0.f, 0.f, 0.f, 0.f};
    acc = __builtin_amdgcn_mfma_f32_16x16x32_bf16(aQ0, b0, acc, 0, 0, 0);
    acc = __builtin_amdgcn_mfma_f32_16x16x32_bf16(aQ1, b1, acc, 0, 0, 0);
    #pragma unroll
    for (int r = 0; r < 4; ++r) S[lg * 4 + r][col0 + lr] = acc[r];
  }
  __syncthreads();

  // softmax: wave wid owns rows 4*wid .. 4*wid+3
  size_t attn_base = ((size_t)(bh * SL + rt * 16)) * SL;
  #pragma unroll
  for (int rr = 0; rr < 4; ++rr) {
    int r = wid * 4 + rr;
    float vv[16];
    float m = -1e30f;
    #pragma unroll
    for (int i = 0; i < 16; ++i) { vv[i] = S[r][l + 64 * i]; m = fmaxf(m, vv[i]); }
    #pragma unroll
    for (int o = 32; o; o >>= 1) m = fmaxf(m, __shfl_xor(m, o));
    float s = 0.f;
    #pragma unroll
    for (int i = 0; i < 16; ++i) { vv[i] = __expf(vv[i] - m); s += vv[i]; }
    #pragma unroll
    for (int o = 32; o; o >>= 1) s += __shfl_xor(s, o);
    float inv = 1.0f / s;
    float* arow = attn_out + attn_base + (size_t)r * SL;
    #pragma unroll
    for (int i = 0; i < 16; ++i) {
      float p = vv[i] * inv;
      arow[l + 64 * i] = p;
      P[r][l + 64 * i] = f2bfbits(p);
    }
  }
  __syncthreads();

  // PV: wave wid -> O cols [wid*16, wid*16+16)
  const ushort* Vbase = VhT + (size_t)bh * DH * SL + (size_t)(wid * 16 + lr) * SL + lg * 8;
  f32x4 acc = {0.f, 0.f, 0.f, 0.f};
  #pragma unroll 8
  for (int kt = 0; kt < 32; ++kt) {
    bf16x8 aP = *(const bf16x8*)(&P[lr][kt * 32 + lg * 8]);
    bf16x8 bV = *(const bf16x8*)(Vbase + kt * 32);
    acc = __builtin_amdgcn_mfma_f32_16x16x32_bf16(aP, bV, acc, 0, 0, 0);
  }
  #pragma unroll
  for (int r = 0; r < 4; ++r)
    O[((size_t)(bh * SL + rt * 16 + lg * 4 + r)) * DH + wid * 16 + lr] = acc[r];
}

// ---------- 6) partial reduce for s: partial[b][slab][d] ----------
__global__ __launch_bounds__(256) void k_reduce(const float* __restrict__ O, float* __restrict__ partial) {
  int slab = blockIdx.x, bb = blockIdx.y;
  int d = threadIdx.x & 63, sub = threadIdx.x >> 6;
  float s = 0.f;
  for (int h = 0; h < NH; ++h) {
    const float* base = O + ((size_t)((bb * NH + h) * SL + slab * 32 + sub * 8)) * DH + d;
    #pragma unroll
    for (int li = 0; li < 8; ++li) s += base[(size_t)li * DH];
  }
  __shared__ float red[4][64];
  red[sub][d] = s;
  __syncthreads();
  if (threadIdx.x < 64) {
    float t = red[0][d] + red[1][d] + red[2][d] + red[3][d];
    partial[(bb * 32 + slab) * 64 + d] = t;
  }
}

// ---------- 7) gate: s @ w_sk, softmax over heads ----------
__global__ __launch_bounds__(256) void k_gate(const float* __restrict__ partial,
                                              const float* __restrict__ wsk, float* __restrict__ g) {
  int bb = blockIdx.x;
  int t = threadIdx.x;
  __shared__ float red[4][64];
  __shared__ float sl[64];
  __shared__ float logit[512];
  int d = t & 63, q4 = t >> 6;
  float s = 0.f;
  for (int i = 0; i < 8; ++i) s += partial[(bb * 32 + q4 * 8 + i) * 64 + d];
  red[q4][d] = s;
  __syncthreads();
  if (t < 64) sl[t] = (red[0][t] + red[1][t] + red[2][t] + red[3][t]) * (1.0f / 1024.0f);
  __syncthreads();
  #pragma unroll
  for (int jj = 0; jj < 2; ++jj) {
    int j = t + jj * 256;
    float lg = 0.f;
    #pragma unroll 8
    for (int c = 0; c < 64; ++c) lg += sl[c] * wsk[c * DM + j];
    logit[j] = lg;
  }
  __syncthreads();
  if (t < 64) {
    float m = -1e30f;
    #pragma unroll
    for (int h = 0; h < NH; ++h) m = fmaxf(m, logit[h * 64 + t]);
    float sum = 0.f, e[NH];
    #pragma unroll
    for (int h = 0; h < NH; ++h) { e[h] = __expf(logit[h * 64 + t] - m); sum += e[h]; }
    float inv = 1.0f / sum;
    #pragma unroll
    for (int h = 0; h < NH; ++h) g[bb * DM + h * 64 + t] = e[h] * inv;
  }
}

// ---------- 8) gate O -> qo, qo @ w_fc + residual, LayerNorm ----------
__global__ __launch_bounds__(256) void k_final(
    const float* __restrict__ O, const float* __restrict__ g, const ushort* __restrict__ wfc,
    const float* __restrict__ q, const float* __restrict__ gamma, const float* __restrict__ beta,
    float* __restrict__ out) {
  __shared__ __align__(16) ushort wl[32768];   // w_fc bf16, 16B-chunk swizzled [d][i8][jg]
  __shared__ __align__(16) float qo[16][64];
  __shared__ __align__(16) float gl[512];
  int lt = blockIdx.x, bb = blockIdx.y;
  int t = threadIdx.x;

  gl[t] = g[bb * DM + t];
  gl[t + 256] = g[bb * DM + 256 + t];
  {
    int jg2 = t & 15, hi = t >> 4;
    #pragma unroll
    for (int m = 0; m < 16; ++m) {
      int di = m * 16 + hi;             // 0..255
      int d = di >> 2, i8 = di & 3;
      bf16x8 w8 = *(const bf16x8*)(wfc + d * DM + jg2 * 32 + i8 * 8);
      *(bf16x8*)(wl + (size_t)(d * 64 + i8 * 16 + jg2) * 8) = w8;
    }
  }
  __syncthreads();

  int r = t >> 4, jg = t & 15;
  int l = lt * 16 + r;
  {
    float4 acc; acc.x = acc.y = acc.z = acc.w = 0.f;
    #pragma unroll
    for (int h = 0; h < NH; ++h) {
      float4 ov = *(const float4*)(O + ((size_t)((bb * NH + h) * SL + l)) * DH + jg * 4);
      float4 gv = *(const float4*)(gl + h * 64 + jg * 4);
      acc.x += ov.x * gv.x; acc.y += ov.y * gv.y; acc.z += ov.z * gv.z; acc.w += ov.w * gv.w;
    }
    *(float4*)&qo[r][jg * 4] = acc;
  }
  __syncthreads();

  float val[32];
  const float* qrow = q + ((size_t)(bb * SL + l)) * DM + jg * 32;
  #pragma unroll
  for (int i4 = 0; i4 < 8; ++i4) *(float4*)&val[i4 * 4] = *(const float4*)(qrow + i4 * 4);

  for (int d = 0; d < 64; ++d) {
    float qd = qo[r][d];
    #pragma unroll
    for (int i8 = 0; i8 < 4; ++i8) {
      bf16x8 wv8 = *(const bf16x8*)(wl + (size_t)(d * 64 + i8 * 16 + jg) * 8);
      #pragma unroll
      for (int e = 0; e < 8; ++e) val[i8 * 8 + e] += qd * bf2f(wv8[e]);
    }
  }

  float s = 0.f, ss = 0.f;
  #pragma unroll
  for (int i = 0; i < 32; ++i) { s += val[i]; ss += val[i] * val[i]; }
  #pragma unroll
  for (int m = 1; m < 16; m <<= 1) { s += __shfl_xor(s, m, 16); ss += __shfl_xor(ss, m, 16); }
  float mu = s * (1.0f / 512.0f);
  float var = ss * (1.0f / 512.0f) - mu * mu;
  float rstd = rsqrtf(var + 1e-6f);

  float* orow = out + ((size_t)(bb * SL + l)) * DM + jg * 32;
  const float* gam = gamma + jg * 32;
  const float* bet = beta + jg * 32;
  #pragma unroll
  for (int i = 0; i < 32; ++i)
    orow[i] = (val[i] - mu) * rstd * gam[i] + bet[i];
}

extern "C" void kernel_launch(void* const* d_in, const int* in_sizes, int n_in,
                              void* d_out, int out_size, void* d_ws, size_t ws_size,
                              hipStream_t stream) {
  (void)in_sizes; (void)n_in; (void)out_size; (void)ws_size;
  const float* q     = (const float*)d_in[0];
  const float* k     = (const float*)d_in[1];
  const float* v     = (const float*)d_in[2];
  const float* w_qs  = (const float*)d_in[3];
  const float* w_ks  = (const float*)d_in[4];
  const float* w_vs  = (const float*)d_in[5];
  const float* w_sk  = (const float*)d_in[6];
  const float* w_fc  = (const float*)d_in[7];
  const float* gamma = (const float*)d_in[8];
  const float* beta  = (const float*)d_in[9];

  float* out  = (float*)d_out;
  float* attn = out + (size_t)NB * SL * DM;   // 2,097,152 floats

  char* wsb = (char*)d_ws;                    // needs ~33.6 MB
  ushort* qb   = (ushort*)(wsb + 0);
  ushort* kb   = (ushort*)(wsb + 4194304);
  ushort* vb   = (ushort*)(wsb + 8388608);
  ushort* wqT  = (ushort*)(wsb + 12582912);
  ushort* wkT  = (ushort*)(wsb + 13107200);
  ushort* wvT  = (ushort*)(wsb + 13631488);
  ushort* wfcb = (ushort*)(wsb + 14155776);
  ushort* Qh   = (ushort*)(wsb + 14221312);
  ushort* Kh   = (ushort*)(wsb + 18415616);
  ushort* VhT  = (ushort*)(wsb + 22609920);
  float*  O    = (float*)(wsb + 26804224);
  float*  part = (float*)(wsb + 35192832);
  float*  gbuf = (float*)(wsb + 35225600);

  k_cvt_act<<<dim3(2048), dim3(256), 0, stream>>>(q, k, v, qb, kb, vb);
  k_cvt_wT<<<dim3(8, 8, 3), dim3(256), 0, stream>>>(w_qs, w_ks, w_vs, wqT, wkT, wvT);
  k_cvt_wfc<<<dim3(32), dim3(256), 0, stream>>>(w_fc, wfcb);
  k_proj<<<dim3(64, 8, 3), dim3(256), 0, stream>>>(qb, kb, vb, wqT, wkT, wvT, Qh, Kh, VhT);
  k_attn<<<dim3(64, 8, 4), dim3(256), 0, stream>>>(Qh, Kh, VhT, attn, O);
  k_reduce<<<dim3(32, 4), dim3(256), 0, stream>>>(O, part);
  k_gate<<<dim3(4), dim3(256), 0, stream>>>(part, w_sk, gbuf);
  k_final<<<dim3(64, 4), dim3(256), 0, stream>>>(O, gbuf, wfcb, q, gamma, beta, out);
}

// Round 2
// 169.076 us; speedup vs baseline: 1.1636x; 1.1636x over previous
//
#include <hip/hip_runtime.h>
#include <hip/hip_bf16.h>
#include <cstdint>

#define NH 8
#define DM 512
#define DH 64
#define NB 4
#define SL 1024

typedef __attribute__((ext_vector_type(8))) short bf16x8;
typedef __attribute__((ext_vector_type(4))) float f32x4;

static __device__ __forceinline__ float bf2f(short s) {
  union { unsigned int u; float f; } c;
  c.u = ((unsigned int)(unsigned short)s) << 16;
  return c.f;
}
static __device__ __forceinline__ unsigned short f2bfbits(float f) {
  union { float f; unsigned int u; } c; c.f = f;
  unsigned int lsb = (c.u >> 16) & 1u;
  unsigned int r = c.u + 0x7fffu + lsb;   // RNE (inputs are finite/normal)
  return (unsigned short)(r >> 16);
}

// ---------- 1) fp32 -> bf16 for q,k,v (each [4096,512]) ----------
__global__ __launch_bounds__(256) void k_cvt_act(
    const float* __restrict__ q, const float* __restrict__ k, const float* __restrict__ v,
    ushort* __restrict__ qb, ushort* __restrict__ kb, ushort* __restrict__ vb) {
  int i = blockIdx.x * 256 + threadIdx.x;   // float4 group, 524288 total
  {
    float4 f = ((const float4*)q)[i];
    ushort4 r = { f2bfbits(f.x), f2bfbits(f.y), f2bfbits(f.z), f2bfbits(f.w) };
    *(ushort4*)(qb + 4 * i) = r;
  }
  {
    float4 f = ((const float4*)k)[i];
    ushort4 r = { f2bfbits(f.x), f2bfbits(f.y), f2bfbits(f.z), f2bfbits(f.w) };
    *(ushort4*)(kb + 4 * i) = r;
  }
  {
    float4 f = ((const float4*)v)[i];
    ushort4 r = { f2bfbits(f.x), f2bfbits(f.y), f2bfbits(f.z), f2bfbits(f.w) };
    *(ushort4*)(vb + 4 * i) = r;
  }
}

// ---------- 2) transpose-convert W [512,512] -> W^T bf16 ----------
__global__ __launch_bounds__(256) void k_cvt_wT(
    const float* __restrict__ w0, const float* __restrict__ w1, const float* __restrict__ w2,
    ushort* __restrict__ o0, ushort* __restrict__ o1, ushort* __restrict__ o2) {
  __shared__ ushort tile[64][65];
  const float* src = blockIdx.z == 0 ? w0 : (blockIdx.z == 1 ? w1 : w2);
  ushort* dst = blockIdx.z == 0 ? o0 : (blockIdx.z == 1 ? o1 : o2);
  int k0 = blockIdx.x * 64, n0 = blockIdx.y * 64;
  int t = threadIdx.x;
  #pragma unroll
  for (int i = 0; i < 16; ++i) {
    int lin = t + i * 256, r = lin >> 6, c = lin & 63;
    tile[r][c] = f2bfbits(src[(size_t)(k0 + r) * DM + n0 + c]);
  }
  __syncthreads();
  #pragma unroll
  for (int i = 0; i < 16; ++i) {
    int lin = t + i * 256, r = lin >> 6, c = lin & 63;
    dst[(size_t)(n0 + r) * DM + k0 + c] = tile[c][r];
  }
}

// ---------- 3) w_fc [64,512] -> bf16 ----------
__global__ __launch_bounds__(256) void k_cvt_wfc(const float* __restrict__ w, ushort* __restrict__ o) {
  int i = blockIdx.x * 256 + threadIdx.x;   // 8192 float4 groups
  float4 f = ((const float4*)w)[i];
  ushort4 r = { f2bfbits(f.x), f2bfbits(f.y), f2bfbits(f.z), f2bfbits(f.w) };
  *(ushort4*)(o + 4 * i) = r;
}

// ---------- 4) projection GEMM: [4096,512]bf16 @ W^T -> heads ----------
// z=0: Q (scale 1/8, out [B,H,L,64]); z=1: K (out [B,H,L,64]); z=2: V (out [B,H,64,L] transposed)
__global__ __launch_bounds__(256) void k_proj(
    const ushort* __restrict__ qb, const ushort* __restrict__ kb, const ushort* __restrict__ vb,
    const ushort* __restrict__ wqT, const ushort* __restrict__ wkT, const ushort* __restrict__ wvT,
    ushort* __restrict__ Qh, ushort* __restrict__ Kh, ushort* __restrict__ VhT) {
  int z = blockIdx.z;
  const ushort* A = z == 0 ? qb : (z == 1 ? kb : vb);
  const ushort* W = z == 0 ? wqT : (z == 1 ? wkT : wvT);
  ushort* Out = z == 0 ? Qh : (z == 1 ? Kh : VhT);
  float scale = z == 0 ? 0.125f : 1.0f;

  int wid = threadIdx.x >> 6, l = threadIdx.x & 63;
  int lr = l & 15, lg = l >> 4;
  int row0 = blockIdx.x * 64 + wid * 16;
  int col0 = blockIdx.y * 64;
  const ushort* Arow = A + (size_t)(row0 + lr) * DM + lg * 8;

  f32x4 acc0 = {0.f, 0.f, 0.f, 0.f}, acc1 = acc0, acc2 = acc0, acc3 = acc0;
  #pragma unroll 4
  for (int kt = 0; kt < 16; ++kt) {
    bf16x8 a = *(const bf16x8*)(Arow + kt * 32);
    bf16x8 b0 = *(const bf16x8*)(W + (size_t)(col0 + 0 * 16 + lr) * DM + kt * 32 + lg * 8);
    bf16x8 b1 = *(const bf16x8*)(W + (size_t)(col0 + 1 * 16 + lr) * DM + kt * 32 + lg * 8);
    bf16x8 b2 = *(const bf16x8*)(W + (size_t)(col0 + 2 * 16 + lr) * DM + kt * 32 + lg * 8);
    bf16x8 b3 = *(const bf16x8*)(W + (size_t)(col0 + 3 * 16 + lr) * DM + kt * 32 + lg * 8);
    acc0 = __builtin_amdgcn_mfma_f32_16x16x32_bf16(a, b0, acc0, 0, 0, 0);
    acc1 = __builtin_amdgcn_mfma_f32_16x16x32_bf16(a, b1, acc1, 0, 0, 0);
    acc2 = __builtin_amdgcn_mfma_f32_16x16x32_bf16(a, b2, acc2, 0, 0, 0);
    acc3 = __builtin_amdgcn_mfma_f32_16x16x32_bf16(a, b3, acc3, 0, 0, 0);
  }
  f32x4 accs[4] = {acc0, acc1, acc2, acc3};
  #pragma unroll
  for (int ct = 0; ct < 4; ++ct) {
    int gcol = col0 + ct * 16 + lr;
    int h = gcol >> 6, d = gcol & 63;
    #pragma unroll
    for (int r = 0; r < 4; ++r) {
      int grow = row0 + lg * 4 + r;
      int bb = grow >> 10, li = grow & 1023;
      float val = accs[ct][r] * scale;
      size_t addr;
      if (z == 2) addr = ((size_t)((bb * NH + h) * DH + d)) * SL + li;
      else        addr = ((size_t)((bb * NH + h) * SL + li)) * DH + d;
      Out[addr] = f2bfbits(val);
    }
  }
}

// ---------- 5) fused attention: QK^T -> softmax -> attn out + PV ----------
// bf16 logits in a 32 KB XOR-swizzled LDS buffer, reused in place for P.
__global__ __launch_bounds__(256, 4) void k_attn(
    const ushort* __restrict__ Qh, const ushort* __restrict__ Kh, const ushort* __restrict__ VhT,
    float* __restrict__ attn_out, float* __restrict__ O) {
  __shared__ __align__(16) ushort Sl[16 * 1024];   // 32 KB, byte ^= (row&7)<<4
  __shared__ float wmax[4][16];

  int rt = blockIdx.x, h = blockIdx.y, bb = blockIdx.z;
  int bh = bb * NH + h;
  int wid = threadIdx.x >> 6, l = threadIdx.x & 63;
  int lr = l & 15, lg = l >> 4;
  char* Sb = (char*)Sl;

  const ushort* Qbase = Qh + ((size_t)(bh * SL + rt * 16 + lr)) * DH + lg * 8;
  bf16x8 aQ0 = *(const bf16x8*)(Qbase);
  bf16x8 aQ1 = *(const bf16x8*)(Qbase + 32);
  const ushort* Kbase = Kh + (size_t)bh * SL * DH;

  // QK^T: wave wid covers cols [wid*256, wid*256+256); row-max tracked in regs
  float mloc[4] = {-1e30f, -1e30f, -1e30f, -1e30f};
  #pragma unroll 4
  for (int ct = 0; ct < 16; ++ct) {
    int col0 = wid * 256 + ct * 16;
    const ushort* kp = Kbase + (size_t)(col0 + lr) * DH + lg * 8;
    bf16x8 b0 = *(const bf16x8*)(kp);
    bf16x8 b1 = *(const bf16x8*)(kp + 32);
    f32x4 acc = {0.f, 0.f, 0.f, 0.f};
    acc = __builtin_amdgcn_mfma_f32_16x16x32_bf16(aQ0, b0, acc, 0, 0, 0);
    acc = __builtin_amdgcn_mfma_f32_16x16x32_bf16(aQ1, b1, acc, 0, 0, 0);
    #pragma unroll
    for (int r = 0; r < 4; ++r) {
      int row = lg * 4 + r;
      ushort us = f2bfbits(acc[r]);
      *(ushort*)(Sb + (((row << 11) + ((col0 + lr) << 1)) ^ ((row & 7) << 4))) = us;
      mloc[r] = fmaxf(mloc[r], bf2f(us));
    }
  }
  // reduce max across the 16 lanes (cols) sharing a row
  #pragma unroll
  for (int r = 0; r < 4; ++r) {
    float m = mloc[r];
    m = fmaxf(m, __shfl_xor(m, 1));
    m = fmaxf(m, __shfl_xor(m, 2));
    m = fmaxf(m, __shfl_xor(m, 4));
    m = fmaxf(m, __shfl_xor(m, 8));
    if (lr == 0) wmax[wid][lg * 4 + r] = m;
  }
  __syncthreads();

  // softmax: wave wid owns rows 4*wid .. 4*wid+3, all in registers
  size_t attn_base = ((size_t)(bh * SL + rt * 16)) * SL;
  #pragma unroll
  for (int rr = 0; rr < 4; ++rr) {
    int r = wid * 4 + rr;
    float M = fmaxf(fmaxf(wmax[0][r], wmax[1][r]), fmaxf(wmax[2][r], wmax[3][r]));
    float e[16];
    float s = 0.f;
    #pragma unroll
    for (int i = 0; i < 16; ++i) {
      float v = bf2f(*(ushort*)(Sb + (((r << 11) + ((l + 64 * i) << 1)) ^ ((r & 7) << 4))));
      e[i] = __expf(v - M); s += e[i];
    }
    #pragma unroll
    for (int o = 32; o; o >>= 1) s += __shfl_xor(s, o);
    float inv = 1.0f / s;
    float* arow = attn_out + attn_base + (size_t)r * SL;
    #pragma unroll
    for (int i = 0; i < 16; ++i) {
      float p = e[i] * inv;
      arow[l + 64 * i] = p;
      *(ushort*)(Sb + (((r << 11) + ((l + 64 * i) << 1)) ^ ((r & 7) << 4))) = f2bfbits(p);
    }
  }
  __syncthreads();

  // PV: wave wid -> O cols [wid*16, wid*16+16)
  const ushort* Vbase = VhT + (size_t)bh * DH * SL + (size_t)(wid * 16 + lr) * SL + lg * 8;
  f32x4 acc = {0.f, 0.f, 0.f, 0.f};
  #pragma unroll 8
  for (int kt = 0; kt < 32; ++kt) {
    bf16x8 aP = *(const bf16x8*)(Sb + (((lr << 11) + ((kt * 32 + lg * 8) << 1)) ^ ((lr & 7) << 4)));
    bf16x8 bV = *(const bf16x8*)(Vbase + kt * 32);
    acc = __builtin_amdgcn_mfma_f32_16x16x32_bf16(aP, bV, acc, 0, 0, 0);
  }
  #pragma unroll
  for (int r = 0; r < 4; ++r)
    O[((size_t)(bh * SL + rt * 16 + lg * 4 + r)) * DH + wid * 16 + lr] = acc[r];
}

// ---------- 6) partial reduce for s: partial[b][slab][d] ----------
__global__ __launch_bounds__(256) void k_reduce(const float* __restrict__ O, float* __restrict__ partial) {
  int slab = blockIdx.x, bb = blockIdx.y;
  int d = threadIdx.x & 63, sub = threadIdx.x >> 6;
  float s = 0.f;
  for (int h = 0; h < NH; ++h) {
    const float* base = O + ((size_t)((bb * NH + h) * SL + slab * 32 + sub * 8)) * DH + d;
    #pragma unroll
    for (int li = 0; li < 8; ++li) s += base[(size_t)li * DH];
  }
  __shared__ float red[4][64];
  red[sub][d] = s;
  __syncthreads();
  if (threadIdx.x < 64) {
    float t = red[0][d] + red[1][d] + red[2][d] + red[3][d];
    partial[(bb * 32 + slab) * 64 + d] = t;
  }
}

// ---------- 7) gate: s @ w_sk, softmax over heads ----------
__global__ __launch_bounds__(256) void k_gate(const float* __restrict__ partial,
                                              const float* __restrict__ wsk, float* __restrict__ g) {
  int bb = blockIdx.x;
  int t = threadIdx.x;
  __shared__ float red[4][64];
  __shared__ float sl[64];
  __shared__ float logit[512];
  int d = t & 63, q4 = t >> 6;
  float s = 0.f;
  for (int i = 0; i < 8; ++i) s += partial[(bb * 32 + q4 * 8 + i) * 64 + d];
  red[q4][d] = s;
  __syncthreads();
  if (t < 64) sl[t] = (red[0][t] + red[1][t] + red[2][t] + red[3][t]) * (1.0f / 1024.0f);
  __syncthreads();
  #pragma unroll
  for (int jj = 0; jj < 2; ++jj) {
    int j = t + jj * 256;
    float lg = 0.f;
    #pragma unroll 8
    for (int c = 0; c < 64; ++c) lg += sl[c] * wsk[c * DM + j];
    logit[j] = lg;
  }
  __syncthreads();
  if (t < 64) {
    float m = -1e30f;
    #pragma unroll
    for (int h = 0; h < NH; ++h) m = fmaxf(m, logit[h * 64 + t]);
    float sum = 0.f, e[NH];
    #pragma unroll
    for (int h = 0; h < NH; ++h) { e[h] = __expf(logit[h * 64 + t] - m); sum += e[h]; }
    float inv = 1.0f / sum;
    #pragma unroll
    for (int h = 0; h < NH; ++h) g[bb * DM + h * 64 + t] = e[h] * inv;
  }
}

// ---------- 8) gate O -> qo, qo @ w_fc + residual, LayerNorm ----------
__global__ __launch_bounds__(256) void k_final(
    const float* __restrict__ O, const float* __restrict__ g, const ushort* __restrict__ wfc,
    const float* __restrict__ q, const float* __restrict__ gamma, const float* __restrict__ beta,
    float* __restrict__ out) {
  __shared__ __align__(16) ushort wl[32768];   // w_fc bf16, 16B-chunk swizzled [d][i8][jg]
  __shared__ __align__(16) float qo[16][64];
  __shared__ __align__(16) float gl[512];
  int lt = blockIdx.x, bb = blockIdx.y;
  int t = threadIdx.x;

  gl[t] = g[bb * DM + t];
  gl[t + 256] = g[bb * DM + 256 + t];
  {
    int jg2 = t & 15, hi = t >> 4;
    #pragma unroll
    for (int m = 0; m < 16; ++m) {
      int di = m * 16 + hi;             // 0..255
      int d = di >> 2, i8 = di & 3;
      bf16x8 w8 = *(const bf16x8*)(wfc + d * DM + jg2 * 32 + i8 * 8);
      *(bf16x8*)(wl + (size_t)(d * 64 + i8 * 16 + jg2) * 8) = w8;
    }
  }
  __syncthreads();

  int r = t >> 4, jg = t & 15;
  int l = lt * 16 + r;
  {
    float4 acc; acc.x = acc.y = acc.z = acc.w = 0.f;
    #pragma unroll
    for (int h = 0; h < NH; ++h) {
      float4 ov = *(const float4*)(O + ((size_t)((bb * NH + h) * SL + l)) * DH + jg * 4);
      float4 gv = *(const float4*)(gl + h * 64 + jg * 4);
      acc.x += ov.x * gv.x; acc.y += ov.y * gv.y; acc.z += ov.z * gv.z; acc.w += ov.w * gv.w;
    }
    *(float4*)&qo[r][jg * 4] = acc;
  }
  __syncthreads();

  float val[32];
  const float* qrow = q + ((size_t)(bb * SL + l)) * DM + jg * 32;
  #pragma unroll
  for (int i4 = 0; i4 < 8; ++i4) *(float4*)&val[i4 * 4] = *(const float4*)(qrow + i4 * 4);

  for (int d = 0; d < 64; ++d) {
    float qd = qo[r][d];
    #pragma unroll
    for (int i8 = 0; i8 < 4; ++i8) {
      bf16x8 wv8 = *(const bf16x8*)(wl + (size_t)(d * 64 + i8 * 16 + jg) * 8);
      #pragma unroll
      for (int e = 0; e < 8; ++e) val[i8 * 8 + e] += qd * bf2f(wv8[e]);
    }
  }

  float s = 0.f, ss = 0.f;
  #pragma unroll
  for (int i = 0; i < 32; ++i) { s += val[i]; ss += val[i] * val[i]; }
  #pragma unroll
  for (int m = 1; m < 16; m <<= 1) { s += __shfl_xor(s, m, 16); ss += __shfl_xor(ss, m, 16); }
  float mu = s * (1.0f / 512.0f);
  float var = ss * (1.0f / 512.0f) - mu * mu;
  float rstd = rsqrtf(var + 1e-6f);

  float* orow = out + ((size_t)(bb * SL + l)) * DM + jg * 32;
  const float* gam = gamma + jg * 32;
  const float* bet = beta + jg * 32;
  #pragma unroll
  for (int i = 0; i < 32; ++i)
    orow[i] = (val[i] - mu) * rstd * gam[i] + bet[i];
}

extern "C" void kernel_launch(void* const* d_in, const int* in_sizes, int n_in,
                              void* d_out, int out_size, void* d_ws, size_t ws_size,
                              hipStream_t stream) {
  (void)in_sizes; (void)n_in; (void)out_size; (void)ws_size;
  const float* q     = (const float*)d_in[0];
  const float* k     = (const float*)d_in[1];
  const float* v     = (const float*)d_in[2];
  const float* w_qs  = (const float*)d_in[3];
  const float* w_ks  = (const float*)d_in[4];
  const float* w_vs  = (const float*)d_in[5];
  const float* w_sk  = (const float*)d_in[6];
  const float* w_fc  = (const float*)d_in[7];
  const float* gamma = (const float*)d_in[8];
  const float* beta  = (const float*)d_in[9];

  float* out  = (float*)d_out;
  float* attn = out + (size_t)NB * SL * DM;   // 2,097,152 floats

  char* wsb = (char*)d_ws;                    // needs ~35.3 MB
  ushort* qb   = (ushort*)(wsb + 0);
  ushort* kb   = (ushort*)(wsb + 4194304);
  ushort* vb   = (ushort*)(wsb + 8388608);
  ushort* wqT  = (ushort*)(wsb + 12582912);
  ushort* wkT  = (ushort*)(wsb + 13107200);
  ushort* wvT  = (ushort*)(wsb + 13631488);
  ushort* wfcb = (ushort*)(wsb + 14155776);
  ushort* Qh   = (ushort*)(wsb + 14221312);
  ushort* Kh   = (ushort*)(wsb + 18415616);
  ushort* VhT  = (ushort*)(wsb + 22609920);
  float*  O    = (float*)(wsb + 26804224);
  float*  part = (float*)(wsb + 35192832);
  float*  gbuf = (float*)(wsb + 35225600);

  k_cvt_act<<<dim3(2048), dim3(256), 0, stream>>>(q, k, v, qb, kb, vb);
  k_cvt_wT<<<dim3(8, 8, 3), dim3(256), 0, stream>>>(w_qs, w_ks, w_vs, wqT, wkT, wvT);
  k_cvt_wfc<<<dim3(32), dim3(256), 0, stream>>>(w_fc, wfcb);
  k_proj<<<dim3(64, 8, 3), dim3(256), 0, stream>>>(qb, kb, vb, wqT, wkT, wvT, Qh, Kh, VhT);
  k_attn<<<dim3(64, 8, 4), dim3(256), 0, stream>>>(Qh, Kh, VhT, attn, O);
  k_reduce<<<dim3(32, 4), dim3(256), 0, stream>>>(O, part);
  k_gate<<<dim3(4), dim3(256), 0, stream>>>(part, w_sk, gbuf);
  k_final<<<dim3(64, 4), dim3(256), 0, stream>>>(O, gbuf, wfcb, q, gamma, beta, out);
}